// Round 5
// baseline (124.155 us; speedup 1.0000x reference)
//
#include <hip/hip_runtime.h>

#define NPIX 16384   // B*HW
#define LCTX 32
#define DIM  128
#define SCALE 0.125f // 64^-0.5
#define PXW  4       // pixels per wave

// ---------------------------------------------------------------------------
// K0: fold weights.
//   Ms[e][j] (j = h*128+c) = SCALE * sum_d Wq[e][h*64+d] * Wkv[c][h*64+d]
//   Nf[i][j] (i = h*128+c) = sum_d Wkv[c][128+h*64+d] * Wo[h*64+d][j]
// ---------------------------------------------------------------------------
__global__ __launch_bounds__(256)
void fold_kernel(const float* __restrict__ Wq, const float* __restrict__ Wkv,
                 const float* __restrict__ Wo,
                 float* __restrict__ Ms, float* __restrict__ Nf)
{
    const int t = threadIdx.x;
    const int b = blockIdx.x;
    if (b < 128) {
        const int e = b, h = t >> 7, c = t & 127;
        const float4* q4p = reinterpret_cast<const float4*>(Wq + e * 128 + h * 64);
        const float4* k4p = reinterpret_cast<const float4*>(Wkv + c * 256 + h * 64);
        float acc = 0.f;
        #pragma unroll
        for (int d4 = 0; d4 < 16; ++d4) {
            const float4 a = q4p[d4], k = k4p[d4];
            acc += a.x * k.x + a.y * k.y + a.z * k.z + a.w * k.w;
        }
        Ms[e * 256 + t] = SCALE * acc;
    } else {
        const int b2 = b - 128;
        const int i = b2 * 2 + (t >> 7), j = t & 127;
        const int h = i >> 7, c = i & 127;
        const float4* v4p = reinterpret_cast<const float4*>(Wkv + c * 256 + 128 + h * 64);
        float acc = 0.f;
        #pragma unroll
        for (int d4 = 0; d4 < 16; ++d4) {
            const float4 v4 = v4p[d4];
            acc += v4.x * Wo[(h * 64 + d4 * 4 + 0) * 128 + j];
            acc += v4.y * Wo[(h * 64 + d4 * 4 + 1) * 128 + j];
            acc += v4.z * Wo[(h * 64 + d4 * 4 + 2) * 128 + j];
            acc += v4.w * Wo[(h * 64 + d4 * 4 + 3) * 128 + j];
        }
        Nf[i * 128 + j] = acc;
    }
}

// ---------------------------------------------------------------------------
// Fused v2: qk -> two-pass register softmax attention -> out.
// 4 waves/block, 4 px/wave, zero barriers (all LDS wave-private).
// Lane = (h = lane>>5, c0 = lane&31): owns qk/ctxw float4 at j = lane*4.
// ---------------------------------------------------------------------------
__global__ __launch_bounds__(256, 4)
void fused2_kernel(const float* __restrict__ x, const float* __restrict__ ctx,
                   const float* __restrict__ Ms, const float* __restrict__ Nf,
                   const float* __restrict__ bo, float* __restrict__ out)
{
    __shared__ float cw[4][PXW * 256];   // 16 KB: ctxw handoff, wave-private slices

    const int t = threadIdx.x;
    const int w = t >> 6, lane = t & 63;
    const int c0 = lane & 31;
    const int wpx = (blockIdx.x * 4 + w) * PXW;   // wave's first pixel

    // ---- Phase 1: qk4[p] = (x[wpx+p] . Ms[:, lane*4 .. lane*4+3]) ----
    float4 qk4[PXW];
    #pragma unroll
    for (int p = 0; p < PXW; ++p) qk4[p] = make_float4(0.f, 0.f, 0.f, 0.f);
    {
        const float4* ms4 = reinterpret_cast<const float4*>(Ms) + lane;
        #pragma unroll 4
        for (int e4 = 0; e4 < 32; ++e4) {
            float4 xv[PXW];
            #pragma unroll
            for (int p = 0; p < PXW; ++p)
                xv[p] = reinterpret_cast<const float4*>(x + (size_t)(wpx + p) * DIM)[e4];
            #pragma unroll
            for (int d = 0; d < 4; ++d) {
                const float4 m4 = ms4[(e4 * 4 + d) * 64];
                #pragma unroll
                for (int p = 0; p < PXW; ++p) {
                    const float xe = (d == 0) ? xv[p].x : (d == 1) ? xv[p].y
                                   : (d == 2) ? xv[p].z : xv[p].w;
                    qk4[p].x += xe * m4.x; qk4[p].y += xe * m4.y;
                    qk4[p].z += xe * m4.z; qk4[p].w += xe * m4.w;
                }
            }
        }
    }

    // ---- Phase 2: per-pixel attention, two-pass, sims in registers ----
    #pragma unroll
    for (int p = 0; p < PXW; ++p) {
        const float4* cb =
            reinterpret_cast<const float4*>(ctx + (size_t)(wpx + p) * LCTX * DIM) + c0;

        // pass A: 32 independent row chains -> sim[r] (wave-uniform per half)
        float sim[LCTX];
        #pragma unroll
        for (int r = 0; r < LCTX; ++r) {
            const float4 cv = cb[r * 32];
            float part = cv.x * qk4[p].x + cv.y * qk4[p].y
                       + cv.z * qk4[p].z + cv.w * qk4[p].w;
            #pragma unroll
            for (int off = 16; off >= 1; off >>= 1) part += __shfl_xor(part, off);
            sim[r] = part;
        }

        // in-lane softmax: register max tree + exp + sum (no cross-lane ops)
        float mx = sim[0];
        #pragma unroll
        for (int r = 1; r < LCTX; ++r) mx = fmaxf(mx, sim[r]);
        float dn = 0.f;
        #pragma unroll
        for (int r = 0; r < LCTX; ++r) { sim[r] = __expf(sim[r] - mx); dn += sim[r]; }
        const float inv = 1.f / dn;

        // pass B: acc = sum_r attn_r * ctx_r  (re-read; L1/L2-hot).
        // Opaque pointer copy stops the compiler CSE-ing 32 float4 loads
        // from pass A into long-lived registers (spill risk).
        uintptr_t ub = (uintptr_t)cb;
        asm volatile("" : "+v"(ub));
        const float4* cbB = (const float4*)ub;

        float4 acc = make_float4(0.f, 0.f, 0.f, 0.f);
        #pragma unroll
        for (int r = 0; r < LCTX; ++r) {
            const float4 cv = cbB[r * 32];
            const float a = sim[r] * inv;
            acc.x += a * cv.x; acc.y += a * cv.y;
            acc.z += a * cv.z; acc.w += a * cv.w;
        }
        reinterpret_cast<float4*>(&cw[w][p * 256])[lane] = acc;
    }
    // same-wave LDS dependency only: no barrier needed (lgkmcnt ordering)

    // ---- Phase 3: out[px][j] = ctxw[px] . Nf[:,j] + bo[j], j = lane*2 ----
    {
        const float2* nf2 = reinterpret_cast<const float2*>(Nf) + lane;
        const float2  b2  = reinterpret_cast<const float2*>(bo)[lane];
        float2 o[PXW];
        #pragma unroll
        for (int p = 0; p < PXW; ++p) o[p] = make_float2(0.f, 0.f);

        #pragma unroll 2
        for (int i4 = 0; i4 < 64; ++i4) {
            float4 a4[PXW];
            #pragma unroll
            for (int p = 0; p < PXW; ++p)
                a4[p] = reinterpret_cast<const float4*>(&cw[w][p * 256])[i4];  // broadcast
            #pragma unroll
            for (int d = 0; d < 4; ++d) {
                const float2 n2 = nf2[(i4 * 4 + d) * 64];
                #pragma unroll
                for (int p = 0; p < PXW; ++p) {
                    const float ae = (d == 0) ? a4[p].x : (d == 1) ? a4[p].y
                                   : (d == 2) ? a4[p].z : a4[p].w;
                    o[p].x += ae * n2.x; o[p].y += ae * n2.y;
                }
            }
        }
        #pragma unroll
        for (int p = 0; p < PXW; ++p) {
            float2 r = o[p];
            r.x += b2.x; r.y += b2.y;
            reinterpret_cast<float2*>(out + (size_t)(wpx + p) * DIM)[lane] = r;
        }
    }
}

// ---------------------------------------------------------------------------
// Fallback: round-1 fused kernel (used only if ws_size is too small).
// ---------------------------------------------------------------------------
#define PPB 8
__global__ __launch_bounds__(256, 4)
void ppca_kernel(const float* __restrict__ x, const float* __restrict__ ctx,
                 const float* __restrict__ Wq, const float* __restrict__ Wkv,
                 const float* __restrict__ Wo, const float* __restrict__ bo,
                 float* __restrict__ out)
{
    __shared__ float smem[4096];
    float* xs    = smem;
    float* qs    = smem + 1024;
    float* qks   = smem + 2048;
    float* attns = smem;
    float* ctxws = smem + 2048;
    float* outs  = smem + 1024;

    const int t = threadIdx.x;
    const int gbase = blockIdx.x * PPB;

    reinterpret_cast<float4*>(xs)[t] =
        reinterpret_cast<const float4*>(x + (size_t)gbase * DIM)[t];
    __syncthreads();

    {
        const int j = t & 127, pg = t >> 7;
        float acc[4] = {0.f, 0.f, 0.f, 0.f};
        for (int k = 0; k < 32; ++k) {
            const float w0 = Wq[(4*k + 0) * DIM + j];
            const float w1 = Wq[(4*k + 1) * DIM + j];
            const float w2 = Wq[(4*k + 2) * DIM + j];
            const float w3 = Wq[(4*k + 3) * DIM + j];
            #pragma unroll
            for (int pp = 0; pp < 4; ++pp) {
                const float4 xv = reinterpret_cast<const float4*>(xs + (pg*4 + pp) * DIM)[k];
                acc[pp] += xv.x*w0 + xv.y*w1 + xv.z*w2 + xv.w*w3;
            }
        }
        #pragma unroll
        for (int pp = 0; pp < 4; ++pp) qs[(pg*4 + pp) * DIM + j] = acc[pp];
    }
    __syncthreads();

    {
        const int c = t & 127, h = t >> 7;
        float acc[PPB] = {0.f,0.f,0.f,0.f,0.f,0.f,0.f,0.f};
        const float4* wrow = reinterpret_cast<const float4*>(Wkv + c * 256 + h * 64);
        for (int k = 0; k < 16; ++k) {
            const float4 w4 = wrow[k];
            #pragma unroll
            for (int p = 0; p < PPB; ++p) {
                const float4 q4 = reinterpret_cast<const float4*>(qs + p * DIM + h * 64)[k];
                acc[p] += q4.x*w4.x + q4.y*w4.y + q4.z*w4.z + q4.w*w4.w;
            }
        }
        #pragma unroll
        for (int p = 0; p < PPB; ++p) qks[(p*2 + h) * DIM + c] = acc[p];
    }
    __syncthreads();

    {
        const int l = t & 31, p = t >> 5;
        const float4* cr = reinterpret_cast<const float4*>(ctx + ((size_t)(gbase + p) * LCTX + l) * DIM);
        const float4* q0 = reinterpret_cast<const float4*>(qks + (p*2 + 0) * DIM);
        const float4* q1 = reinterpret_cast<const float4*>(qks + (p*2 + 1) * DIM);
        float s0 = 0.f, s1 = 0.f;
        #pragma unroll 8
        for (int k = 0; k < 32; ++k) {
            const float4 cv = cr[k], a = q0[k], b = q1[k];
            s0 += cv.x*a.x + cv.y*a.y + cv.z*a.z + cv.w*a.w;
            s1 += cv.x*b.x + cv.y*b.y + cv.z*b.z + cv.w*b.w;
        }
        s0 *= SCALE; s1 *= SCALE;
        float m0 = s0, m1 = s1;
        #pragma unroll
        for (int off = 16; off >= 1; off >>= 1) {
            m0 = fmaxf(m0, __shfl_xor(m0, off));
            m1 = fmaxf(m1, __shfl_xor(m1, off));
        }
        const float e0 = __expf(s0 - m0), e1 = __expf(s1 - m1);
        float d0 = e0, d1 = e1;
        #pragma unroll
        for (int off = 16; off >= 1; off >>= 1) {
            d0 += __shfl_xor(d0, off);
            d1 += __shfl_xor(d1, off);
        }
        attns[(p*2 + 0) * LCTX + l] = e0 / d0;
        attns[(p*2 + 1) * LCTX + l] = e1 / d1;
    }
    __syncthreads();

    {
        const int c = t & 127, pg = t >> 7;
        #pragma unroll
        for (int pp = 0; pp < 4; ++pp) {
            const int p = pg*4 + pp;
            const float* cb = ctx + (size_t)(gbase + p) * LCTX * DIM + c;
            const float4* a0p = reinterpret_cast<const float4*>(attns + (p*2 + 0) * LCTX);
            const float4* a1p = reinterpret_cast<const float4*>(attns + (p*2 + 1) * LCTX);
            float s0 = 0.f, s1 = 0.f;
            #pragma unroll
            for (int q = 0; q < 8; ++q) {
                const float4 a0 = a0p[q], a1 = a1p[q];
                const float c0 = cb[(size_t)(4*q + 0) * DIM];
                const float c1 = cb[(size_t)(4*q + 1) * DIM];
                const float c2 = cb[(size_t)(4*q + 2) * DIM];
                const float c3 = cb[(size_t)(4*q + 3) * DIM];
                s0 += a0.x*c0 + a0.y*c1 + a0.z*c2 + a0.w*c3;
                s1 += a1.x*c0 + a1.y*c1 + a1.z*c2 + a1.w*c3;
            }
            ctxws[(p*2 + 0) * DIM + c] = s0;
            ctxws[(p*2 + 1) * DIM + c] = s1;
        }
    }
    __syncthreads();

    {
        const int i = t & 127, pg = t >> 7, h = i >> 6;
        float acc[4] = {0.f, 0.f, 0.f, 0.f};
        for (int k = 0; k < 32; ++k) {
            const float w0 = Wkv[(4*k + 0) * 256 + 128 + i];
            const float w1 = Wkv[(4*k + 1) * 256 + 128 + i];
            const float w2 = Wkv[(4*k + 2) * 256 + 128 + i];
            const float w3 = Wkv[(4*k + 3) * 256 + 128 + i];
            #pragma unroll
            for (int pp = 0; pp < 4; ++pp) {
                const float4 cw4 = reinterpret_cast<const float4*>(ctxws + ((pg*4 + pp)*2 + h) * DIM)[k];
                acc[pp] += cw4.x*w0 + cw4.y*w1 + cw4.z*w2 + cw4.w*w3;
            }
        }
        #pragma unroll
        for (int pp = 0; pp < 4; ++pp) outs[(pg*4 + pp) * DIM + i] = acc[pp];
    }
    __syncthreads();

    {
        const int j = t & 127, pg = t >> 7;
        float acc[4] = {0.f, 0.f, 0.f, 0.f};
        for (int k = 0; k < 32; ++k) {
            const float w0 = Wo[(4*k + 0) * DIM + j];
            const float w1 = Wo[(4*k + 1) * DIM + j];
            const float w2 = Wo[(4*k + 2) * DIM + j];
            const float w3 = Wo[(4*k + 3) * DIM + j];
            #pragma unroll
            for (int pp = 0; pp < 4; ++pp) {
                const float4 ov = reinterpret_cast<const float4*>(outs + (pg*4 + pp) * DIM)[k];
                acc[pp] += ov.x*w0 + ov.y*w1 + ov.z*w2 + ov.w*w3;
            }
        }
        const float bj = bo[j];
        #pragma unroll
        for (int pp = 0; pp < 4; ++pp)
            out[(size_t)(gbase + pg*4 + pp) * DIM + j] = acc[pp] + bj;
    }
}

extern "C" void kernel_launch(void* const* d_in, const int* in_sizes, int n_in,
                              void* d_out, int out_size, void* d_ws, size_t ws_size,
                              hipStream_t stream) {
    const float* x   = (const float*)d_in[0];
    const float* ctx = (const float*)d_in[1];
    const float* Wq  = (const float*)d_in[2];
    const float* Wkv = (const float*)d_in[3];
    const float* Wo  = (const float*)d_in[4];
    const float* bo  = (const float*)d_in[5];
    float* out = (float*)d_out;

    const size_t needed = (size_t)(32768 + 32768) * sizeof(float);
    if (ws_size < needed) {
        dim3 grid(NPIX / PPB), block(256);
        hipLaunchKernelGGL(ppca_kernel, grid, block, 0, stream,
                           x, ctx, Wq, Wkv, Wo, bo, out);
        return;
    }

    float* Ms = (float*)d_ws;
    float* Nf = Ms + 32768;

    hipLaunchKernelGGL(fold_kernel,  dim3(256), dim3(256), 0, stream, Wq, Wkv, Wo, Ms, Nf);
    hipLaunchKernelGGL(fused2_kernel, dim3(NPIX / (4 * PXW)), dim3(256), 0, stream,
                       x, ctx, Ms, Nf, bo, out);
}